// Round 8
// baseline (138.663 us; speedup 1.0000x reference)
//
#include <hip/hip_runtime.h>
#include <stdint.h>

typedef unsigned short u16;

#define L_SEQ 2048
#define DMODEL 1024
#define NHEAD 16

using f32x4 = __attribute__((ext_vector_type(4))) float;
using s16x8 = __attribute__((ext_vector_type(8))) short;

__device__ __forceinline__ u16 f2b(float f) {
    union { float f; uint32_t u; } v; v.f = f;
    uint32_t r = v.u + 0x7fffu + ((v.u >> 16) & 1u);
    return (u16)(r >> 16);
}

__device__ __forceinline__ void gld16(const void* g, void* l) {
    __builtin_amdgcn_global_load_lds(
        (__attribute__((address_space(1))) void*)(uintptr_t)g,
        (__attribute__((address_space(3))) void*)(uintptr_t)l,
        16, 0, 0);
}

// ---------------- fused f32 -> bf16 convert (x + 4 weights, one launch) ----------------
__global__ __launch_bounds__(256)
void k_tobf16_all(const float* __restrict__ x, const float* __restrict__ wq,
                  const float* __restrict__ wk, const float* __restrict__ wv,
                  const float* __restrict__ wo,
                  u16* __restrict__ xb, u16* __restrict__ wqb, u16* __restrict__ wkb,
                  u16* __restrict__ wvb, u16* __restrict__ wob) {
    const int NX = L_SEQ * DMODEL / 8;     // 262144
    const int NW = DMODEL * DMODEL / 8;    // 131072 = 2^17
    int i = blockIdx.x * blockDim.x + threadIdx.x;
    const float* src; u16* dst; int j;
    if (i < NX) { src = x; dst = xb; j = i; }
    else {
        int t = i - NX; int sel = t >> 17; j = t & (NW - 1);
        src = (sel == 0) ? wq : (sel == 1) ? wk : (sel == 2) ? wv : wo;
        dst = (sel == 0) ? wqb : (sel == 1) ? wkb : (sel == 2) ? wvb : wob;
    }
    const float4* s4 = (const float4*)src;
    float4 a = s4[2 * j], b = s4[2 * j + 1];
    union { s16x8 v; u16 u[8]; } o;
    o.u[0] = f2b(a.x); o.u[1] = f2b(a.y); o.u[2] = f2b(a.z); o.u[3] = f2b(a.w);
    o.u[4] = f2b(b.x); o.u[5] = f2b(b.y); o.u[6] = f2b(b.z); o.u[7] = f2b(b.w);
    ((s16x8*)dst)[j] = o.v;
}

// ---------------- phase features -> packed (c,s) float2 ----------------
__global__ __launch_bounds__(256)
void k_phase(const float* __restrict__ x, const float* __restrict__ Wp,
             const float* __restrict__ bp, float2* __restrict__ CSph) {
    const int tid = threadIdx.x;
    const int w = tid >> 6, lane = tid & 63;
    const int m = blockIdx.x * 4 + w;
    __shared__ float pbuf[4][32];
    float xr[16];
#pragma unroll
    for (int i = 0; i < 16; ++i) xr[i] = x[(size_t)m * DMODEL + lane + 64 * i];
#pragma unroll 4
    for (int n = 0; n < 32; ++n) {
        const float* wrow = Wp + n * DMODEL;
        float s = 0.f;
#pragma unroll
        for (int i = 0; i < 16; ++i) s += xr[i] * wrow[lane + 64 * i];
#pragma unroll
        for (int msk = 32; msk >= 1; msk >>= 1) s += __shfl_xor(s, msk);
        if (lane == 0) pbuf[w][n] = s + bp[n];
    }
    __syncthreads();
    if (lane < 16) {
        float c = pbuf[w][2 * lane], sn = pbuf[w][2 * lane + 1];
        float nrm = sqrtf(c * c + sn * sn);
        float inv = 1.0f / fmaxf(nrm, 1e-6f);
        CSph[(size_t)lane * L_SEQ + m] = make_float2(c * inv, sn * inv);
    }
}

// ---------------- bf16 B^T GEMM (m97 structure, verified R1 — unchanged) ----------------
template <int OUTF32>
__global__ __launch_bounds__(256, 2)
void k_gemm_bt(const u16* __restrict__ A,
               const u16* __restrict__ B0, const u16* __restrict__ B1, const u16* __restrict__ B2,
               const float* __restrict__ c0, const float* __restrict__ c1, const float* __restrict__ c2,
               void* __restrict__ Out, int ldo, int K) {
    __shared__ u16 As[128 * 64];
    __shared__ u16 Bs[128 * 64];
    const int tid = threadIdx.x;
    const int w = tid >> 6, lane = tid & 63;
    const int wr = w >> 1, wc = w & 1;
    const int u = lane & 15, g = lane >> 4;
    const int mt = blockIdx.x, nt = blockIdx.y;
    const int seg = nt >> 3, ntl = nt & 7;
    const u16* Bp = (seg == 0) ? B0 : (seg == 1) ? B1 : B2;
    const float* biasp = (seg == 0) ? c0 : (seg == 1) ? c1 : c2;

    const u16* Ab = A + (size_t)(mt * 128 + w * 32) * K;
    const u16* Bb = Bp + (size_t)(ntl * 128 + w * 32) * K;
    const int lr = lane >> 3;
    const int lc = (lane & 7) * 8;

    f32x4 acc[4][4] = {};

    for (int k0 = 0; k0 < K; k0 += 64) {
#pragma unroll
        for (int c = 0; c < 4; ++c)
            gld16(Ab + (size_t)(c * 8 + lr) * K + k0 + lc, &As[(w * 32 + c * 8) * 64]);
#pragma unroll
        for (int c = 0; c < 4; ++c)
            gld16(Bb + (size_t)(c * 8 + lr) * K + k0 + lc, &Bs[(w * 32 + c * 8) * 64]);
        __syncthreads();
#pragma unroll
        for (int ks = 0; ks < 2; ++ks) {
            s16x8 af[4], bf[4];
#pragma unroll
            for (int i = 0; i < 4; ++i)
                af[i] = *(const s16x8*)&As[(wr * 64 + i * 16 + u) * 64 + ks * 32 + g * 8];
#pragma unroll
            for (int j = 0; j < 4; ++j)
                bf[j] = *(const s16x8*)&Bs[(wc * 64 + j * 16 + u) * 64 + ks * 32 + g * 8];
#pragma unroll
            for (int i = 0; i < 4; ++i)
#pragma unroll
                for (int j = 0; j < 4; ++j)
                    acc[i][j] = __builtin_amdgcn_mfma_f32_16x16x32_bf16(af[i], bf[j], acc[i][j], 0, 0, 0);
        }
        __syncthreads();
    }

#pragma unroll
    for (int i = 0; i < 4; ++i) {
#pragma unroll
        for (int j = 0; j < 4; ++j) {
            const int row0 = mt * 128 + wr * 64 + i * 16 + g * 4;
            const int col = nt * 128 + wc * 64 + j * 16 + u;
            const int colseg = ntl * 128 + wc * 64 + j * 16 + u;
            const float bias = biasp[colseg];
#pragma unroll
            for (int r = 0; r < 4; ++r) {
                float val = acc[i][j][r] + bias;
                if (OUTF32)
                    ((float*)Out)[(size_t)(row0 + r) * ldo + col] = val;
                else
                    ((u16*)Out)[(size_t)(row0 + r) * ldo + col] = f2b(val);
            }
        }
    }
}

// ---------------- V transpose: qkv V section [token][feat] -> VtG [feat][token] ----------------
__global__ __launch_bounds__(256)
void k_transposeV(const u16* __restrict__ qkv, u16* __restrict__ VtG) {
    __shared__ u16 T[64 * 64];
    const int tb = blockIdx.x;
    const int fb = blockIdx.y;
    const int tid = threadIdx.x;
    char* Tb = (char*)T;
#pragma unroll
    for (int t = 0; t < 2; ++t) {
        int ci = t * 256 + tid;
        int r = ci >> 3, cb = ci & 7;
        s16x8 v = *(const s16x8*)(qkv + (size_t)(tb * 64 + r) * (3 * DMODEL) + 2 * DMODEL + fb * 64 + cb * 8);
        int kk = (((r >> 3) ^ r) & 7) << 4;
        *(s16x8*)(Tb + r * 128 + ((cb * 16) ^ kk)) = v;
    }
    __syncthreads();
#pragma unroll
    for (int t = 0; t < 2; ++t) {
        int co = t * 256 + tid;
        int f = co >> 3, t8 = co & 7;
        union { u16 us[8]; s16x8 v; } o;
#pragma unroll
        for (int x = 0; x < 8; ++x) {
            int r = t8 * 8 + x;
            int kk = (((r >> 3) ^ r) & 7) << 4;
            o.us[x] = *(const u16*)(Tb + r * 128 + ((f * 2) ^ kk));
        }
        *(s16x8*)(VtG + (size_t)(fb * 64 + f) * L_SEQ + tb * 64 + t8 * 8) = o.v;
    }
}

// ---------------- fused attention v6: de-lockstepped 2-wave blocks + half-pipelined tile ----------------
// grid (L/32, H), 128 threads = 2 waves, 4 blocks/CU (independent barrier
// domains -> phase-decorrelated waves). Per 64-key tile: QK^T; then halves
// (kb 0-1 / 2-3) pipelined so h1 softmax VALU overlaps h0's P lgkm + PV MFMAs.
__global__ __launch_bounds__(128, 2)
void k_attn(const u16* __restrict__ QKV, const u16* __restrict__ VtG,
            const float2* __restrict__ CSph,
            const float* __restrict__ gamma, u16* __restrict__ Oout) {
    const int h = blockIdx.y;
    const int qb = blockIdx.x * 32;
    const int tid = threadIdx.x;
    const int w = tid >> 6, lane = tid & 63;
    const int u = lane & 15, g = lane >> 4;
    const int ld = 3 * DMODEL;
    const int NT = L_SEQ / 64;
    const int BUF = 64 * 64 * 2;

    __shared__ u16 Ks[2][64 * 64];
    __shared__ u16 Vs[2][64 * 64];
    __shared__ u16 Pl[2][16 * 64];

    const float LOG2E = 1.44269504088896f;
    const float gate2 = (0.08f / (1.0f + __expf(-gamma[h]))) * LOG2E;
    const float SC2 = 0.125f * LOG2E;

    const u16* Qp = QKV + h * 64;
    const u16* Kp = QKV + DMODEL + h * 64;
    const u16* VtH = VtG + (size_t)h * 64 * L_SEQ;
    const float2* CS = CSph + (size_t)h * L_SEQ;

    s16x8 aq0, aq1;
    {
        const int qrow = qb + w * 16 + u;
        aq0 = *(const s16x8*)(Qp + (size_t)qrow * ld + g * 8);
        aq1 = *(const s16x8*)(Qp + (size_t)qrow * ld + 32 + g * 8);
    }
    float gcq[4], gsq[4];
#pragma unroll
    for (int r = 0; r < 4; ++r) {
        float2 cs = CS[qb + w * 16 + g * 4 + r];
        gcq[r] = gate2 * cs.x;
        gsq[r] = gate2 * cs.y;
    }

    union { u16 us[8]; s16x8 v; } one_;
#pragma unroll
    for (int i = 0; i < 8; ++i) one_.us[i] = 0x3F80;   // bf16 1.0
    const s16x8 vone = one_.v;

    // staging: 8KB tile = 512 x 16B chunks; 128 threads x 4 insts.
    // gld16 LDS dest is wave-uniform base + lane*16.
    unsigned dstOff[4];
    size_t srcK[4], srcV[4];
#pragma unroll
    for (int t = 0; t < 4; ++t) {
        int ci = t * 128 + w * 64 + lane;
        int row = ci >> 3, cb = ci & 7;
        dstOff[t] = (unsigned)(t * 2048 + w * 1024);
        srcK[t] = (size_t)row * ld + (size_t)((cb ^ (row & 7)) * 8);
        srcV[t] = (size_t)row * L_SEQ + (size_t)((cb ^ (row & 7)) * 8);
    }
    char* ksBase = (char*)Ks;
    char* vsBase = (char*)Vs;
    char* PlB = (char*)Pl + w * 2048;

    // prologue: stage tile 0
#pragma unroll
    for (int t = 0; t < 4; ++t) {
        gld16(Kp + srcK[t], ksBase + dstOff[t]);
        gld16(VtH + srcV[t], vsBase + dstOff[t]);
    }
    __syncthreads();

    float mrow[4];
    f32x4 lacc = {};
    f32x4 oacc[4] = {};
#pragma unroll
    for (int r = 0; r < 4; ++r) mrow[r] = -1e30f;

    float2 cskN[4];
#pragma unroll
    for (int kb = 0; kb < 4; ++kb) cskN[kb] = CS[kb * 16 + u];

    for (int kt = 0; kt < NT; ++kt) {
        const int cur = kt & 1;
        const char* kCur = ksBase + cur * BUF;
        const char* vCur = vsBase + cur * BUF;

        // V fragments from LDS, issued early
        s16x8 vbr[4][2];
#pragma unroll
        for (int ks = 0; ks < 2; ++ks) {
            const int xv = (ks * 64 + g * 16) ^ ((u & 7) << 4);
#pragma unroll
            for (int db = 0; db < 4; ++db)
                vbr[db][ks] = *(const s16x8*)(vCur + (db * 16 + u) * 128 + xv);
        }

        float ck4[4], sk4[4];
#pragma unroll
        for (int kb = 0; kb < 4; ++kb) { ck4[kb] = cskN[kb].x; sk4[kb] = cskN[kb].y; }
        if (kt + 1 < NT) {
#pragma unroll
            for (int kb = 0; kb < 4; ++kb)
                cskN[kb] = CS[(kt + 1) * 64 + kb * 16 + u];
        }

        // prefetch next K/V tile
        if (kt + 1 < NT) {
            const u16* Kn = Kp + (size_t)(kt + 1) * 64 * ld;
            const u16* Vn = VtH + (size_t)(kt + 1) * 64;
            char* kN = ksBase + (cur ^ 1) * BUF;
            char* vN = vsBase + (cur ^ 1) * BUF;
#pragma unroll
            for (int t = 0; t < 4; ++t) {
                gld16(Kn + srcK[t], kN + dstOff[t]);
                gld16(Vn + srcV[t], vN + dstOff[t]);
            }
        }

        // ---- S = Q K^T ----
        f32x4 sf[4] = {};
        const int x0 = (g * 16) ^ ((u & 7) << 4);
        __builtin_amdgcn_s_setprio(1);
#pragma unroll
        for (int kb = 0; kb < 4; ++kb) {
            const int rowb = (kb * 16 + u) * 128;
            s16x8 b0 = *(const s16x8*)(kCur + rowb + x0);
            s16x8 b1 = *(const s16x8*)(kCur + rowb + (x0 ^ 64));
            sf[kb] = __builtin_amdgcn_mfma_f32_16x16x32_bf16(aq0, b0, sf[kb], 0, 0, 0);
            sf[kb] = __builtin_amdgcn_mfma_f32_16x16x32_bf16(aq1, b1, sf[kb], 0, 0, 0);
        }
        __builtin_amdgcn_s_setprio(0);

        float sv[4][4];

        // ---- half 0 (kb 0,1): bias + lane-local max ----
        float tmax0[4];
#pragma unroll
        for (int r = 0; r < 4; ++r) tmax0[r] = -1e30f;
#pragma unroll
        for (int kb = 0; kb < 2; ++kb)
#pragma unroll
            for (int r = 0; r < 4; ++r) {
                float xv = sf[kb][r] * SC2 + gcq[r] * ck4[kb] + gsq[r] * sk4[kb];
                sv[kb][r] = xv;
                tmax0[r] = fmaxf(tmax0[r], xv);
            }
        bool need0 = false;
#pragma unroll
        for (int r = 0; r < 4; ++r) need0 |= (tmax0[r] > mrow[r] + 4.0f);
        if (__any(need0)) {
            float scl[4];
#pragma unroll
            for (int r = 0; r < 4; ++r) {
                float t = tmax0[r];
#pragma unroll
                for (int msk = 1; msk <= 8; msk <<= 1)
                    t = fmaxf(t, __shfl_xor(t, msk));
                float mn = fmaxf(mrow[r], t);
                scl[r] = __builtin_amdgcn_exp2f(mrow[r] - mn);
                mrow[r] = mn;
            }
#pragma unroll
            for (int db = 0; db < 4; ++db)
#pragma unroll
                for (int r = 0; r < 4; ++r)
                    oacc[db][r] *= scl[r];
#pragma unroll
            for (int r = 0; r < 4; ++r) lacc[r] *= scl[r];
        }
        // P(h0) -> LDS
#pragma unroll
        for (int kb = 0; kb < 2; ++kb)
#pragma unroll
            for (int r = 0; r < 4; ++r) {
                float p = __builtin_amdgcn_exp2f(sv[kb][r] - mrow[r]);
                int prow = g * 4 + r;
                int pb = prow * 128 + (kb * 16 + u) * 2;
                pb ^= (prow & 7) << 4;
                *(u16*)(PlB + pb) = f2b(p);
            }

        // ---- half 1 (kb 2,3): bias + lane-local max (VALU overlaps h0 lgkm/PV) ----
        float tmax1[4];
#pragma unroll
        for (int r = 0; r < 4; ++r) tmax1[r] = -1e30f;
#pragma unroll
        for (int kb = 2; kb < 4; ++kb)
#pragma unroll
            for (int r = 0; r < 4; ++r) {
                float xv = sf[kb][r] * SC2 + gcq[r] * ck4[kb] + gsq[r] * sk4[kb];
                sv[kb][r] = xv;
                tmax1[r] = fmaxf(tmax1[r], xv);
            }

        // ---- PV half 0 ----
        {
            s16x8 pa = *(const s16x8*)(PlB + u * 128 + ((g * 16) ^ ((u & 7) << 4)));
            __builtin_amdgcn_s_setprio(1);
            lacc = __builtin_amdgcn_mfma_f32_16x16x32_bf16(pa, vone, lacc, 0, 0, 0);
#pragma unroll
            for (int db = 0; db < 4; ++db)
                oacc[db] = __builtin_amdgcn_mfma_f32_16x16x32_bf16(pa, vbr[db][0], oacc[db], 0, 0, 0);
            __builtin_amdgcn_s_setprio(0);
        }

        // ---- half 1 defer-check + P write ----
        bool need1 = false;
#pragma unroll
        for (int r = 0; r < 4; ++r) need1 |= (tmax1[r] > mrow[r] + 4.0f);
        if (__any(need1)) {
            float scl[4];
#pragma unroll
            for (int r = 0; r < 4; ++r) {
                float t = tmax1[r];
#pragma unroll
                for (int msk = 1; msk <= 8; msk <<= 1)
                    t = fmaxf(t, __shfl_xor(t, msk));
                float mn = fmaxf(mrow[r], t);
                scl[r] = __builtin_amdgcn_exp2f(mrow[r] - mn);
                mrow[r] = mn;
            }
#pragma unroll
            for (int db = 0; db < 4; ++db)
#pragma unroll
                for (int r = 0; r < 4; ++r)
                    oacc[db][r] *= scl[r];
#pragma unroll
            for (int r = 0; r < 4; ++r) lacc[r] *= scl[r];
        }
#pragma unroll
        for (int kb = 2; kb < 4; ++kb)
#pragma unroll
            for (int r = 0; r < 4; ++r) {
                float p = __builtin_amdgcn_exp2f(sv[kb][r] - mrow[r]);
                int prow = g * 4 + r;
                int pb = prow * 128 + (kb * 16 + u) * 2;
                pb ^= (prow & 7) << 4;
                *(u16*)(PlB + pb) = f2b(p);
            }

        // ---- PV half 1 ----
        {
            s16x8 pa = *(const s16x8*)(PlB + u * 128 + ((64 + g * 16) ^ ((u & 7) << 4)));
            __builtin_amdgcn_s_setprio(1);
            lacc = __builtin_amdgcn_mfma_f32_16x16x32_bf16(pa, vone, lacc, 0, 0, 0);
#pragma unroll
            for (int db = 0; db < 4; ++db)
                oacc[db] = __builtin_amdgcn_mfma_f32_16x16x32_bf16(pa, vbr[db][1], oacc[db], 0, 0, 0);
            __builtin_amdgcn_s_setprio(0);
        }
        __syncthreads();
    }

#pragma unroll
    for (int db = 0; db < 4; ++db)
#pragma unroll
        for (int r = 0; r < 4; ++r) {
            int qr = qb + w * 16 + g * 4 + r;
            int col = h * 64 + db * 16 + u;
            Oout[(size_t)qr * DMODEL + col] = f2b(oacc[db][r] / lacc[r]);
        }
}

extern "C" void kernel_launch(void* const* d_in, const int* in_sizes, int n_in,
                              void* d_out, int out_size, void* d_ws, size_t ws_size,
                              hipStream_t stream) {
    const float* x  = (const float*)d_in[0];
    const float* Wq = (const float*)d_in[1];
    const float* bq = (const float*)d_in[2];
    const float* Wk = (const float*)d_in[3];
    const float* bk = (const float*)d_in[4];
    const float* Wv = (const float*)d_in[5];
    const float* bv = (const float*)d_in[6];
    const float* Wo = (const float*)d_in[7];
    const float* bo = (const float*)d_in[8];
    const float* Wp = (const float*)d_in[9];
    const float* bp = (const float*)d_in[10];
    const float* gamma = (const float*)d_in[11];
    float* out = (float*)d_out;

    char* ws = (char*)d_ws;
    u16* xb = (u16*)ws;   ws += (size_t)L_SEQ * DMODEL * 2;
    u16* wqb = (u16*)ws;  ws += (size_t)DMODEL * DMODEL * 2;
    u16* wkb = (u16*)ws;  ws += (size_t)DMODEL * DMODEL * 2;
    u16* wvb = (u16*)ws;  ws += (size_t)DMODEL * DMODEL * 2;
    u16* wob = (u16*)ws;  ws += (size_t)DMODEL * DMODEL * 2;
    u16* qkv = (u16*)ws;  ws += (size_t)L_SEQ * 3 * DMODEL * 2;
    u16* attnb = (u16*)ws; ws += (size_t)L_SEQ * DMODEL * 2;
    u16* VtG = (u16*)ws;  ws += (size_t)DMODEL * L_SEQ * 2;
    float2* CSph = (float2*)ws; ws += (size_t)NHEAD * L_SEQ * 8;

    const int ntot8 = (L_SEQ * DMODEL + 4 * DMODEL * DMODEL) / 8;  // 786432
    k_tobf16_all<<<ntot8 / 256, 256, 0, stream>>>(x, Wq, Wk, Wv, Wo, xb, wqb, wkb, wvb, wob);

    k_phase<<<L_SEQ / 4, 256, 0, stream>>>(x, Wp, bp, CSph);

    // fused QKV projection -> qkv [2048, 3072] bf16
    k_gemm_bt<0><<<dim3(16, 24), 256, 0, stream>>>(xb, wqb, wkb, wvb, bq, bk, bv,
                                                   (void*)qkv, 3 * DMODEL, DMODEL);

    // V^T [1024, 2048] bf16
    k_transposeV<<<dim3(L_SEQ / 64, DMODEL / 64), 256, 0, stream>>>(qkv, VtG);

    k_attn<<<dim3(L_SEQ / 32, NHEAD), 128, 0, stream>>>(qkv, VtG, CSph, gamma, attnb);

    // output projection -> d_out f32 [2048, 1024]
    k_gemm_bt<1><<<dim3(16, 8), 256, 0, stream>>>(attnb, wob, wob, wob, bo, bo, bo,
                                                  (void*)out, DMODEL, DMODEL);
}

// Round 9
// 115.671 us; speedup vs baseline: 1.1988x; 1.1988x over previous
//
#include <hip/hip_runtime.h>
#include <stdint.h>

typedef unsigned short u16;

#define L_SEQ 2048
#define DMODEL 1024
#define NHEAD 16

using f32x4 = __attribute__((ext_vector_type(4))) float;
using s16x8 = __attribute__((ext_vector_type(8))) short;

__device__ __forceinline__ u16 f2b(float f) {
    union { float f; uint32_t u; } v; v.f = f;
    uint32_t r = v.u + 0x7fffu + ((v.u >> 16) & 1u);
    return (u16)(r >> 16);
}

__device__ __forceinline__ void gld16(const void* g, void* l) {
    __builtin_amdgcn_global_load_lds(
        (__attribute__((address_space(1))) void*)(uintptr_t)g,
        (__attribute__((address_space(3))) void*)(uintptr_t)l,
        16, 0, 0);
}

// ---------------- merged: f32->bf16 converts (blocks 0..3071) + phase features (blocks 3072..3583) ----------------
__global__ __launch_bounds__(256)
void k_pre(const float* __restrict__ x, const float* __restrict__ wq,
           const float* __restrict__ wk, const float* __restrict__ wv,
           const float* __restrict__ wo,
           u16* __restrict__ xb, u16* __restrict__ wqb, u16* __restrict__ wkb,
           u16* __restrict__ wvb, u16* __restrict__ wob,
           const float* __restrict__ Wp, const float* __restrict__ bp,
           float2* __restrict__ CSph) {
    const int NX = L_SEQ * DMODEL / 8;     // 262144
    const int NW = DMODEL * DMODEL / 8;    // 131072 = 2^17
    const int NCONV = (NX + 4 * NW) / 256; // 3072 blocks
    const int tid = threadIdx.x;
    __shared__ float pbuf[4][32];

    if ((int)blockIdx.x < NCONV) {
        int i = blockIdx.x * 256 + tid;
        const float* src; u16* dst; int j;
        if (i < NX) { src = x; dst = xb; j = i; }
        else {
            int t = i - NX; int sel = t >> 17; j = t & (NW - 1);
            src = (sel == 0) ? wq : (sel == 1) ? wk : (sel == 2) ? wv : wo;
            dst = (sel == 0) ? wqb : (sel == 1) ? wkb : (sel == 2) ? wvb : wob;
        }
        const float4* s4 = (const float4*)src;
        float4 a = s4[2 * j], b = s4[2 * j + 1];
        union { s16x8 v; u16 u[8]; } o;
        o.u[0] = f2b(a.x); o.u[1] = f2b(a.y); o.u[2] = f2b(a.z); o.u[3] = f2b(a.w);
        o.u[4] = f2b(b.x); o.u[5] = f2b(b.y); o.u[6] = f2b(b.z); o.u[7] = f2b(b.w);
        ((s16x8*)dst)[j] = o.v;
        return;
    }

    // phase feature blocks
    const int w = tid >> 6, lane = tid & 63;
    const int m = (blockIdx.x - NCONV) * 4 + w;
    float xr[16];
#pragma unroll
    for (int i = 0; i < 16; ++i) xr[i] = x[(size_t)m * DMODEL + lane + 64 * i];
#pragma unroll 4
    for (int n = 0; n < 32; ++n) {
        const float* wrow = Wp + n * DMODEL;
        float s = 0.f;
#pragma unroll
        for (int i = 0; i < 16; ++i) s += xr[i] * wrow[lane + 64 * i];
#pragma unroll
        for (int msk = 32; msk >= 1; msk >>= 1) s += __shfl_xor(s, msk);
        if (lane == 0) pbuf[w][n] = s + bp[n];
    }
    __syncthreads();
    if (lane < 16) {
        float c = pbuf[w][2 * lane], sn = pbuf[w][2 * lane + 1];
        float nrm = sqrtf(c * c + sn * sn);
        float inv = 1.0f / fmaxf(nrm, 1e-6f);
        CSph[(size_t)lane * L_SEQ + m] = make_float2(c * inv, sn * inv);
    }
}

// ---------------- bf16 B^T GEMM, BM=128 BN=64 BK=64, XOR-swizzled LDS ----------------
// C[m,n] = sum_k A[m,k]*B[n,k] + bias[n].  4 waves (2x2), per-wave 64x32 out.
// Staging uses the attention kernel's verified pattern: pre-swizzled global
// source + linear LDS dest; reads XOR back -> conflict-free.
template <int OUTF32>
__global__ __launch_bounds__(256, 2)
void k_gemm64(const u16* __restrict__ A,
              const u16* __restrict__ B0, const u16* __restrict__ B1, const u16* __restrict__ B2,
              const float* __restrict__ c0, const float* __restrict__ c1, const float* __restrict__ c2,
              void* __restrict__ Out, int ldo, int K) {
    __shared__ u16 As[128 * 64];
    __shared__ u16 Bs[64 * 64];
    const int tid = threadIdx.x;
    const int w = tid >> 6, lane = tid & 63;
    const int wr = w >> 1, wc = w & 1;
    const int u = lane & 15, g = lane >> 4;
    const int lr = lane >> 3;          // 0..7
    const int cb = lane & 7;           // col octet
    const int mt = blockIdx.x, nt = blockIdx.y;
    const int seg = nt >> 4, ntl = nt & 15;
    const u16* Bp = (seg == 0) ? B0 : (seg == 1) ? B1 : B2;
    const float* biasp = (seg == 0) ? c0 : (seg == 1) ? c1 : c2;

    const u16* Ab = A + (size_t)(mt * 128 + w * 32) * K;
    const u16* Bb = Bp + (size_t)(ntl * 64) * K;
    char* asB = (char*)As;
    char* bsB = (char*)Bs;

    f32x4 acc[4][2] = {};

    for (int k0 = 0; k0 < K; k0 += 64) {
        // A: 128x64 tile, 4 chunks/thread (row = w*32 + c*8 + lr)
#pragma unroll
        for (int c = 0; c < 4; ++c)
            gld16(Ab + (size_t)(c * 8 + lr) * K + k0 + ((cb ^ lr) * 8),
                  asB + (w * 32 + c * 8) * 128);
        // B: 64x64 tile, 2 chunks/thread (row = t*32 + w*8 + lr)
#pragma unroll
        for (int t = 0; t < 2; ++t)
            gld16(Bb + (size_t)(t * 32 + w * 8 + lr) * K + k0 + ((cb ^ lr) * 8),
                  bsB + t * 4096 + w * 1024);
        __syncthreads();
        const int x0 = (g * 16) ^ ((u & 7) << 4);
#pragma unroll
        for (int ks = 0; ks < 2; ++ks) {
            s16x8 af[4], bf[2];
#pragma unroll
            for (int i = 0; i < 4; ++i)
                af[i] = *(const s16x8*)(asB + (wr * 64 + i * 16 + u) * 128 + (x0 ^ (ks * 64)));
#pragma unroll
            for (int j = 0; j < 2; ++j)
                bf[j] = *(const s16x8*)(bsB + (wc * 32 + j * 16 + u) * 128 + (x0 ^ (ks * 64)));
#pragma unroll
            for (int i = 0; i < 4; ++i)
#pragma unroll
                for (int j = 0; j < 2; ++j)
                    acc[i][j] = __builtin_amdgcn_mfma_f32_16x16x32_bf16(af[i], bf[j], acc[i][j], 0, 0, 0);
        }
        __syncthreads();
    }

#pragma unroll
    for (int i = 0; i < 4; ++i) {
#pragma unroll
        for (int j = 0; j < 2; ++j) {
            const int row0 = mt * 128 + wr * 64 + i * 16 + g * 4;
            const int col = nt * 64 + wc * 32 + j * 16 + u;
            const int colseg = ntl * 64 + wc * 32 + j * 16 + u;
            const float bias = biasp[colseg];
#pragma unroll
            for (int r = 0; r < 4; ++r) {
                float val = acc[i][j][r] + bias;
                if (OUTF32)
                    ((float*)Out)[(size_t)(row0 + r) * ldo + col] = val;
                else
                    ((u16*)Out)[(size_t)(row0 + r) * ldo + col] = f2b(val);
            }
        }
    }
}

// ---------------- V transpose: qkv V section [token][feat] -> VtG [feat][token] (verified R4) ----------------
__global__ __launch_bounds__(256)
void k_transposeV(const u16* __restrict__ qkv, u16* __restrict__ VtG) {
    __shared__ u16 T[64 * 64];
    const int tb = blockIdx.x;
    const int fb = blockIdx.y;
    const int tid = threadIdx.x;
    char* Tb = (char*)T;
#pragma unroll
    for (int t = 0; t < 2; ++t) {
        int ci = t * 256 + tid;
        int r = ci >> 3, cb = ci & 7;
        s16x8 v = *(const s16x8*)(qkv + (size_t)(tb * 64 + r) * (3 * DMODEL) + 2 * DMODEL + fb * 64 + cb * 8);
        int kk = (((r >> 3) ^ r) & 7) << 4;
        *(s16x8*)(Tb + r * 128 + ((cb * 16) ^ kk)) = v;
    }
    __syncthreads();
#pragma unroll
    for (int t = 0; t < 2; ++t) {
        int co = t * 256 + tid;
        int f = co >> 3, t8 = co & 7;
        union { u16 us[8]; s16x8 v; } o;
#pragma unroll
        for (int x = 0; x < 8; ++x) {
            int r = t8 * 8 + x;
            int kk = (((r >> 3) ^ r) & 7) << 4;
            o.us[x] = *(const u16*)(Tb + r * 128 + ((f * 2) ^ kk));
        }
        *(s16x8*)(VtG + (size_t)(fb * 64 + f) * L_SEQ + tb * 64 + t8 * 8) = o.v;
    }
}

// ---------------- fused attention (R6-measured 57us version, verbatim) ----------------
__global__ __launch_bounds__(256, 2)
void k_attn(const u16* __restrict__ QKV, const u16* __restrict__ VtG,
            const float2* __restrict__ CSph,
            const float* __restrict__ gamma, u16* __restrict__ Oout) {
    const int h = blockIdx.y;
    const int qb = blockIdx.x * 64;
    const int tid = threadIdx.x;
    const int w = tid >> 6, lane = tid & 63;
    const int u = lane & 15, g = lane >> 4;
    const int ld = 3 * DMODEL;
    const int NT = L_SEQ / 64;
    const int BUF = 64 * 64 * 2;

    __shared__ u16 Ks[2][64 * 64];
    __shared__ u16 Vs[2][64 * 64];
    __shared__ u16 Pl[4][16 * 64];

    const float LOG2E = 1.44269504088896f;
    const float gate2 = (0.08f / (1.0f + __expf(-gamma[h]))) * LOG2E;
    const float SC2 = 0.125f * LOG2E;

    const u16* Qp = QKV + h * 64;
    const u16* Kp = QKV + DMODEL + h * 64;
    const u16* VtH = VtG + (size_t)h * 64 * L_SEQ;
    const float2* CS = CSph + (size_t)h * L_SEQ;

    s16x8 aq0, aq1;
    {
        const int qrow = qb + w * 16 + u;
        aq0 = *(const s16x8*)(Qp + (size_t)qrow * ld + g * 8);
        aq1 = *(const s16x8*)(Qp + (size_t)qrow * ld + 32 + g * 8);
    }
    float gcq[4], gsq[4];
#pragma unroll
    for (int r = 0; r < 4; ++r) {
        float2 cs = CS[qb + w * 16 + g * 4 + r];
        gcq[r] = gate2 * cs.x;
        gsq[r] = gate2 * cs.y;
    }

    union { u16 us[8]; s16x8 v; } one_;
#pragma unroll
    for (int i = 0; i < 8; ++i) one_.us[i] = 0x3F80;   // bf16 1.0
    const s16x8 vone = one_.v;

    unsigned dstOff[2];
    size_t srcK[2], srcV[2];
#pragma unroll
    for (int t = 0; t < 2; ++t) {
        int ci = (w * 2 + t) * 64 + lane;
        int row = ci >> 3, cb = ci & 7;
        dstOff[t] = (unsigned)((w * 2 + t) * 1024);
        srcK[t] = (size_t)row * ld + (size_t)((cb ^ (row & 7)) * 8);
        srcV[t] = (size_t)row * L_SEQ + (size_t)((cb ^ (row & 7)) * 8);
    }
    char* ksBase = (char*)Ks;
    char* vsBase = (char*)Vs;
    char* PlB = (char*)Pl + w * 2048;

#pragma unroll
    for (int t = 0; t < 2; ++t) {
        gld16(Kp + srcK[t], ksBase + dstOff[t]);
        gld16(VtH + srcV[t], vsBase + dstOff[t]);
    }
    __syncthreads();

    float mrow[4];
    f32x4 lacc = {};
    f32x4 oacc[4] = {};
#pragma unroll
    for (int r = 0; r < 4; ++r) mrow[r] = -1e30f;

    float2 cskN[4];
#pragma unroll
    for (int kb = 0; kb < 4; ++kb) cskN[kb] = CS[kb * 16 + u];

    for (int kt = 0; kt < NT; ++kt) {
        const int cur = kt & 1;
        const char* kCur = ksBase + cur * BUF;
        const char* vCur = vsBase + cur * BUF;

        s16x8 vbr[4][2];
#pragma unroll
        for (int ks = 0; ks < 2; ++ks) {
            const int xv = (ks * 64 + g * 16) ^ ((u & 7) << 4);
#pragma unroll
            for (int db = 0; db < 4; ++db)
                vbr[db][ks] = *(const s16x8*)(vCur + (db * 16 + u) * 128 + xv);
        }

        float ck4[4], sk4[4];
#pragma unroll
        for (int kb = 0; kb < 4; ++kb) { ck4[kb] = cskN[kb].x; sk4[kb] = cskN[kb].y; }
        if (kt + 1 < NT) {
#pragma unroll
            for (int kb = 0; kb < 4; ++kb)
                cskN[kb] = CS[(kt + 1) * 64 + kb * 16 + u];
        }

        if (kt + 1 < NT) {
            const u16* Kn = Kp + (size_t)(kt + 1) * 64 * ld;
            const u16* Vn = VtH + (size_t)(kt + 1) * 64;
            char* kN = ksBase + (cur ^ 1) * BUF;
            char* vN = vsBase + (cur ^ 1) * BUF;
#pragma unroll
            for (int t = 0; t < 2; ++t) {
                gld16(Kn + srcK[t], kN + dstOff[t]);
                gld16(Vn + srcV[t], vN + dstOff[t]);
            }
        }

        // ---- S = Q K^T ----
        f32x4 sf[4] = {};
        const int x0 = (g * 16) ^ ((u & 7) << 4);
#pragma unroll
        for (int kb = 0; kb < 4; ++kb) {
            const int rowb = (kb * 16 + u) * 128;
            s16x8 b0 = *(const s16x8*)(kCur + rowb + x0);
            s16x8 b1 = *(const s16x8*)(kCur + rowb + (x0 ^ 64));
            sf[kb] = __builtin_amdgcn_mfma_f32_16x16x32_bf16(aq0, b0, sf[kb], 0, 0, 0);
            sf[kb] = __builtin_amdgcn_mfma_f32_16x16x32_bf16(aq1, b1, sf[kb], 0, 0, 0);
        }

        // ---- bias + lane-local max ----
        float sv[4][4], tmax[4];
#pragma unroll
        for (int r = 0; r < 4; ++r) tmax[r] = -1e30f;
#pragma unroll
        for (int kb = 0; kb < 4; ++kb)
#pragma unroll
            for (int r = 0; r < 4; ++r) {
                float xv = sf[kb][r] * SC2 + gcq[r] * ck4[kb] + gsq[r] * sk4[kb];
                sv[kb][r] = xv;
                tmax[r] = fmaxf(tmax[r], xv);
            }

        // ---- deferred max ----
        bool need = false;
#pragma unroll
        for (int r = 0; r < 4; ++r) need |= (tmax[r] > mrow[r] + 4.0f);
        if (__any(need)) {
            float scl[4];
#pragma unroll
            for (int r = 0; r < 4; ++r) {
                float t = tmax[r];
#pragma unroll
                for (int msk = 1; msk <= 8; msk <<= 1)
                    t = fmaxf(t, __shfl_xor(t, msk));
                float mn = fmaxf(mrow[r], t);
                scl[r] = __builtin_amdgcn_exp2f(mrow[r] - mn);
                mrow[r] = mn;
            }
#pragma unroll
            for (int db = 0; db < 4; ++db)
#pragma unroll
                for (int r = 0; r < 4; ++r)
                    oacc[db][r] *= scl[r];
#pragma unroll
            for (int r = 0; r < 4; ++r) lacc[r] *= scl[r];
        }

        // ---- P = exp2(S - m) -> LDS ----
#pragma unroll
        for (int kb = 0; kb < 4; ++kb)
#pragma unroll
            for (int r = 0; r < 4; ++r) {
                float p = __builtin_amdgcn_exp2f(sv[kb][r] - mrow[r]);
                int prow = g * 4 + r;
                int pb = prow * 128 + (kb * 16 + u) * 2;
                pb ^= (prow & 7) << 4;
                *(u16*)(PlB + pb) = f2b(p);
            }

        // ---- O += P V ; l += P * ones ----
#pragma unroll
        for (int ks = 0; ks < 2; ++ks) {
            s16x8 pa = *(const s16x8*)(PlB + u * 128 + ((ks * 64 + g * 16) ^ ((u & 7) << 4)));
            lacc = __builtin_amdgcn_mfma_f32_16x16x32_bf16(pa, vone, lacc, 0, 0, 0);
#pragma unroll
            for (int db = 0; db < 4; ++db)
                oacc[db] = __builtin_amdgcn_mfma_f32_16x16x32_bf16(pa, vbr[db][ks], oacc[db], 0, 0, 0);
        }
        __syncthreads();
    }

#pragma unroll
    for (int db = 0; db < 4; ++db)
#pragma unroll
        for (int r = 0; r < 4; ++r) {
            int qr = qb + w * 16 + g * 4 + r;
            int col = h * 64 + db * 16 + u;
            Oout[(size_t)qr * DMODEL + col] = f2b(oacc[db][r] / lacc[r]);
        }
}

extern "C" void kernel_launch(void* const* d_in, const int* in_sizes, int n_in,
                              void* d_out, int out_size, void* d_ws, size_t ws_size,
                              hipStream_t stream) {
    const float* x  = (const float*)d_in[0];
    const float* Wq = (const float*)d_in[1];
    const float* bq = (const float*)d_in[2];
    const float* Wk = (const float*)d_in[3];
    const float* bk = (const float*)d_in[4];
    const float* Wv = (const float*)d_in[5];
    const float* bv = (const float*)d_in[6];
    const float* Wo = (const float*)d_in[7];
    const float* bo = (const float*)d_in[8];
    const float* Wp = (const float*)d_in[9];
    const float* bp = (const float*)d_in[10];
    const float* gamma = (const float*)d_in[11];
    float* out = (float*)d_out;

    char* ws = (char*)d_ws;
    u16* xb = (u16*)ws;   ws += (size_t)L_SEQ * DMODEL * 2;
    u16* wqb = (u16*)ws;  ws += (size_t)DMODEL * DMODEL * 2;
    u16* wkb = (u16*)ws;  ws += (size_t)DMODEL * DMODEL * 2;
    u16* wvb = (u16*)ws;  ws += (size_t)DMODEL * DMODEL * 2;
    u16* wob = (u16*)ws;  ws += (size_t)DMODEL * DMODEL * 2;
    u16* qkv = (u16*)ws;  ws += (size_t)L_SEQ * 3 * DMODEL * 2;
    u16* attnb = (u16*)ws; ws += (size_t)L_SEQ * DMODEL * 2;
    u16* VtG = (u16*)ws;  ws += (size_t)DMODEL * L_SEQ * 2;
    float2* CSph = (float2*)ws; ws += (size_t)NHEAD * L_SEQ * 8;

    // converts (3072 blocks) + phase (512 blocks)
    k_pre<<<3072 + 512, 256, 0, stream>>>(x, Wq, Wk, Wv, Wo, xb, wqb, wkb, wvb, wob,
                                          Wp, bp, CSph);

    // fused QKV projection -> qkv [2048, 3072] bf16  (BM=128, BN=64)
    k_gemm64<0><<<dim3(16, 48), 256, 0, stream>>>(xb, wqb, wkb, wvb, bq, bk, bv,
                                                  (void*)qkv, 3 * DMODEL, DMODEL);

    // V^T [1024, 2048] bf16
    k_transposeV<<<dim3(L_SEQ / 64, DMODEL / 64), 256, 0, stream>>>(qkv, VtG);

    k_attn<<<dim3(L_SEQ / 64, NHEAD), 256, 0, stream>>>(qkv, VtG, CSph, gamma, attnb);

    // output projection -> d_out f32 [2048, 1024]  (256 blocks: full occupancy)
    k_gemm64<1><<<dim3(16, 16), 256, 0, stream>>>(attnb, wob, wob, wob, bo, bo, bo,
                                                  (void*)out, DMODEL, DMODEL);
}